// Round 1
// 815.546 us; speedup vs baseline: 1.6661x; 1.6661x over previous
//
#include <hip/hip_runtime.h>

// Round 4: occupancy attack. k_spatial LDS 139264->67072 (2 blocks/CU),
// k_temporal 111104->51200 (3 blocks/CU):
//  - weight B-fragments read directly from global (L2-resident, shared by all
//    blocks) -> no Wt/WpL LDS staging, A-fragments held in registers.
//  - V written transposed in the qkv epilogue -> no scalar VT-build loop.
//  - wave-parallel register softmax (MFMA C-layout + shfl_xor over lr groups)
//    -> no fp32 S buffer (50KB), no 147-thread serial softmax, P written direct.
// mfma_f32_16x16x32_bf16: A[m=lane&15][k=quad*8+j], B[n=lane&15][k=quad*8+j],
//                         C/D: col=lane&15, row=quad*4+reg
typedef __bf16 bf16x2 __attribute__((ext_vector_type(2)));
typedef __bf16 bf16x4 __attribute__((ext_vector_type(4)));
typedef __bf16 bf16x8 __attribute__((ext_vector_type(8)));
typedef float f32x4 __attribute__((ext_vector_type(4)));
#define MFMA __builtin_amdgcn_mfma_f32_16x16x32_bf16

#define SCALE 0.17677669529663687f   // 1/sqrt(32)
#define QS2 200  // spatial Q|K LDS row stride (bf16); 400B rows, W/4 odd -> conflict-free b128
#define QS3 296  // temporal Q|K|V row stride (bf16)
#define VS 72    // VT row stride (bf16)
#define PS 72    // P row stride (bf16)
#define CS 104   // xt/ctx row stride (bf16)

__device__ __forceinline__ bf16x4 cvt4(const float* p) {
  bf16x4 v;
  float4 f = *(const float4*)p;
  v[0] = (__bf16)f.x; v[1] = (__bf16)f.y; v[2] = (__bf16)f.z; v[3] = (__bf16)f.w;
  return v;
}
__device__ __forceinline__ bf16x4 bz4() {
  bf16x4 z;
  for (int i = 0; i < 4; ++i) z[i] = (__bf16)0.f;
  return z;
}

// ---- K0: transpose+convert weights into ws: WqT[288x96] | WspT[96x96] | WtmT[96x96] ----
__global__ __launch_bounds__(256) void k_transpose(const float* __restrict__ Wq,
    const float* __restrict__ Wsp, const float* __restrict__ Wtm,
    __bf16* __restrict__ ws) {
  const int which = blockIdx.x, tid = threadIdx.x;
  if (which == 0) {
    for (int idx = tid; idx < 27648; idx += 256) {
      int n = idx / 96, k = idx % 96;
      ws[idx] = (__bf16)Wq[k * 288 + n];          // WqT[n][k] = Wq[k][n]
    }
  } else {
    const float* src = (which == 1) ? Wsp : Wtm;
    __bf16* dst = ws + 27648 + (which - 1) * 9216;
    for (int idx = tid; idx < 9216; idx += 256) {
      int n = idx / 96, k = idx % 96;
      dst[idx] = (__bf16)src[k * 96 + n];
    }
  }
}

// ---- K1: spatial: per (b,t): qkv, masked attn (L=49), proj_sp ----
// smem regions (bytes):
//   [0,25600)      qk (Q|K, 64 x QS2)      -> ctx (64 x CS) in phase D
//   [25600,53248)  xt (64 x CS, phase A)   -> P (192 x PS) from phase B
//   [53248,67072)  VT (96 x VS)
__global__ __launch_bounds__(256) void k_spatial(const float* __restrict__ x,
    const __bf16* __restrict__ WqT, const float* __restrict__ qkv_b,
    const float* __restrict__ mask, const __bf16* __restrict__ WpT,
    const float* __restrict__ bp, float* __restrict__ out) {
  __shared__ __align__(16) char smem[67072];
  __bf16* qk  = (__bf16*)(smem);
  __bf16* ctx = (__bf16*)(smem);
  __bf16* xt  = (__bf16*)(smem + 25600);
  __bf16* P   = (__bf16*)(smem + 25600);
  __bf16* VT  = (__bf16*)(smem + 53248);

  const int tid = threadIdx.x;
  const int bt = blockIdx.x;                      // b*8 + t
  const long rbase = (long)bt * 49;
  const int wave = tid >> 6, lane = tid & 63, lr = lane & 15, quad = lane >> 4;

  // ---- phase A: stage x tile (fp32->bf16, pad rows zero); qkv MFMA ----
  const float* xg = x + rbase * 96;
  for (int v = tid; v < 1536; v += 256) {         // 64 rows x 24 float4
    int r = v / 24, c = (v % 24) * 4;
    bf16x4 val = bz4();
    if (r < 49) val = cvt4(&xg[r * 96 + c]);
    *(bf16x4*)&xt[r * CS + c] = val;
  }
  __syncthreads();
  {
    bf16x8 afr[4][3];                             // A fragments in regs, reused over all ct
    for (int rt = 0; rt < 4; ++rt)
      for (int ks = 0; ks < 3; ++ks)
        afr[rt][ks] = *(const bf16x8*)&xt[(rt * 16 + lr) * CS + ks * 32 + quad * 8];
    for (int ct = wave; ct < 18; ct += 4) {       // B fragments straight from L2
      const __bf16* wrow = &WqT[(ct * 16 + lr) * 96 + quad * 8];
      bf16x8 b0 = *(const bf16x8*)&wrow[0];
      bf16x8 b1 = *(const bf16x8*)&wrow[32];
      bf16x8 b2 = *(const bf16x8*)&wrow[64];
      int col = ct * 16 + lr;
      float bv = qkv_b[col];
      for (int rt = 0; rt < 4; ++rt) {
        f32x4 acc = {0.f, 0.f, 0.f, 0.f};
        acc = MFMA(afr[rt][0], b0, acc, 0, 0, 0);
        acc = MFMA(afr[rt][1], b1, acc, 0, 0, 0);
        acc = MFMA(afr[rt][2], b2, acc, 0, 0, 0);
        if (ct < 12) {                            // Q|K -> qk rows
          for (int i = 0; i < 4; ++i)
            qk[(rt * 16 + quad * 4 + i) * QS2 + col] = (__bf16)(acc[i] + bv);
        } else {                                  // V -> VT transposed, packed 4B
          int d = col - 192;
          __bf16* vp = &VT[d * VS + rt * 16 + quad * 4];
          bf16x2 lo; lo[0] = (__bf16)(acc[0] + bv); lo[1] = (__bf16)(acc[1] + bv);
          bf16x2 hi; hi[0] = (__bf16)(acc[2] + bv); hi[1] = (__bf16)(acc[3] + bv);
          *(bf16x2*)&vp[0] = lo;
          *(bf16x2*)&vp[2] = hi;
        }
      }
    }
  }
  __syncthreads();                                // xt dead; P takes its region

  // ---- phase B: scores + wave-parallel register softmax -> P ----
  // wave w owns row-tile rt=w; lane holds S[n=rt*16+quad*4+i][m=ct*16+lr].
  // m>=49 forced to -1e30 -> P cols 49..63 == 0, so V/K pad rows (bias) are inert.
  {
    const int rt = wave;
    const int nb = rt * 16 + quad * 4;
    const float* mrow = mask + (long)(bt & 63) * 2401;
    for (int h = 0; h < 3; ++h) {
      bf16x8 qf = *(const bf16x8*)&qk[(rt * 16 + lr) * QS2 + h * 32 + quad * 8];
      float sv[4][4];
      for (int ct = 0; ct < 4; ++ct) {
        bf16x8 kf = *(const bf16x8*)&qk[(ct * 16 + lr) * QS2 + 96 + h * 32 + quad * 8];
        f32x4 acc = {0.f, 0.f, 0.f, 0.f};
        acc = MFMA(qf, kf, acc, 0, 0, 0);
        int m = ct * 16 + lr;
        int mm = (m < 49) ? m : 48;               // clamp keeps loads in-bounds
        for (int i = 0; i < 4; ++i) {
          int nn = (nb + i < 49) ? nb + i : 48;
          float mv = mrow[nn * 49 + mm];
          sv[ct][i] = (m < 49) ? (acc[i] * SCALE + mv) : -1e30f;
        }
      }
      for (int i = 0; i < 4; ++i) {
        float mx = fmaxf(fmaxf(sv[0][i], sv[1][i]), fmaxf(sv[2][i], sv[3][i]));
        mx = fmaxf(mx, __shfl_xor(mx, 1));
        mx = fmaxf(mx, __shfl_xor(mx, 2));
        mx = fmaxf(mx, __shfl_xor(mx, 4));
        mx = fmaxf(mx, __shfl_xor(mx, 8));
        float e0 = __expf(sv[0][i] - mx), e1 = __expf(sv[1][i] - mx);
        float e2 = __expf(sv[2][i] - mx), e3 = __expf(sv[3][i] - mx);
        float sum = e0 + e1 + e2 + e3;
        sum += __shfl_xor(sum, 1);
        sum += __shfl_xor(sum, 2);
        sum += __shfl_xor(sum, 4);
        sum += __shfl_xor(sum, 8);
        float inv = 1.f / sum;
        __bf16* Pr = &P[(h * 64 + nb + i) * PS + lr];
        Pr[0]  = (__bf16)(e0 * inv);
        Pr[16] = (__bf16)(e1 * inv);
        Pr[32] = (__bf16)(e2 * inv);
        Pr[48] = (__bf16)(e3 * inv);
      }
    }
  }
  __syncthreads();                                // qk dead; ctx takes its region

  // ---- phase C: PV -> ctx ----
  for (int tile = wave; tile < 24; tile += 4) {
    int h = tile / 8, rt = (tile / 2) & 3, dt = tile & 1;
    f32x4 acc = {0.f, 0.f, 0.f, 0.f};
    for (int ks = 0; ks < 2; ++ks) {
      bf16x8 a  = *(const bf16x8*)&P[(h * 64 + rt * 16 + lr) * PS + ks * 32 + quad * 8];
      bf16x8 bb = *(const bf16x8*)&VT[(h * 32 + dt * 16 + lr) * VS + ks * 32 + quad * 8];
      acc = MFMA(a, bb, acc, 0, 0, 0);
    }
    for (int i = 0; i < 4; ++i)
      ctx[(rt * 16 + quad * 4 + i) * CS + h * 32 + dt * 16 + lr] = (__bf16)acc[i];
  }
  __syncthreads();

  // ---- phase D: proj -> out, B fragments from L2 ----
  for (int tile = wave; tile < 24; tile += 4) {
    int rt = tile / 6, ct = tile % 6;
    int col = ct * 16 + lr;
    const __bf16* wrow = &WpT[col * 96 + quad * 8];
    f32x4 acc = {0.f, 0.f, 0.f, 0.f};
    for (int ks = 0; ks < 3; ++ks) {
      bf16x8 a  = *(const bf16x8*)&ctx[(rt * 16 + lr) * CS + ks * 32 + quad * 8];
      bf16x8 bb = *(const bf16x8*)&wrow[ks * 32];
      acc = MFMA(a, bb, acc, 0, 0, 0);
    }
    float bv = bp[col];
    for (int i = 0; i < 4; ++i) {
      int r = rt * 16 + quad * 4 + i;
      if (r < 49) out[(rbase + r) * 96 + col] = acc[i] + bv;
    }
  }
}

// ---- K2: temporal: per (b, 8-n group): qkv fused, attn over T=8, proj_temp ----
// smem: [0,37888) qk 64xQS3 | [37888,51200) xt (phase A) -> ctx (later)
__global__ __launch_bounds__(256) void k_temporal(const float* __restrict__ x,
    const __bf16* __restrict__ WqT, const float* __restrict__ qkv_b,
    const __bf16* __restrict__ WpT, const float* __restrict__ bp,
    float* __restrict__ out) {
  __shared__ __align__(16) char smem[51200];
  __bf16* qk  = (__bf16*)(smem);
  __bf16* xt  = (__bf16*)(smem + 37888);
  __bf16* ctx = (__bf16*)(smem + 37888);

  const int tid = threadIdx.x;
  const int n0 = blockIdx.x * 8;
  const int b = blockIdx.y;
  const int wave = tid >> 6, lane = tid & 63, lr = lane & 15, quad = lane >> 4;

  // ---- phase A: stage x rows (r = t*8+ni); qkv MFMA with global-B ----
  for (int v = tid; v < 1536; v += 256) {
    int r = v / 24, c = (v % 24) * 4;
    int t = r >> 3, n = n0 + (r & 7);
    bf16x4 val = bz4();
    if (n < 49) val = cvt4(&x[((long)(b * 8 + t) * 49 + n) * 96 + c]);
    *(bf16x4*)&xt[r * CS + c] = val;
  }
  __syncthreads();
  {
    bf16x8 afr[4][3];
    for (int rt = 0; rt < 4; ++rt)
      for (int ks = 0; ks < 3; ++ks)
        afr[rt][ks] = *(const bf16x8*)&xt[(rt * 16 + lr) * CS + ks * 32 + quad * 8];
    for (int ct = wave; ct < 18; ct += 4) {
      const __bf16* wrow = &WqT[(ct * 16 + lr) * 96 + quad * 8];
      bf16x8 b0 = *(const bf16x8*)&wrow[0];
      bf16x8 b1 = *(const bf16x8*)&wrow[32];
      bf16x8 b2 = *(const bf16x8*)&wrow[64];
      int col = ct * 16 + lr;
      float bv = qkv_b[col];
      for (int rt = 0; rt < 4; ++rt) {
        f32x4 acc = {0.f, 0.f, 0.f, 0.f};
        acc = MFMA(afr[rt][0], b0, acc, 0, 0, 0);
        acc = MFMA(afr[rt][1], b1, acc, 0, 0, 0);
        acc = MFMA(afr[rt][2], b2, acc, 0, 0, 0);
        for (int i = 0; i < 4; ++i)
          qk[(rt * 16 + quad * 4 + i) * QS3 + col] = (__bf16)(acc[i] + bv);
      }
    }
  }
  __syncthreads();

  // ---- phase B: per-thread 8x8 attention -> ctx (aliases dead xt) ----
  if (tid < 192) {                                 // task = i*24 + h*8 + ni
    int ni = tid & 7, h = (tid >> 3) % 3, i = tid / 24;
    const int ro = h * 32;
    float q[32];
    for (int d = 0; d < 32; ++d) q[d] = (float)qk[(i * 8 + ni) * QS3 + ro + d];
    float s[8], mx = -1e30f;
    for (int j = 0; j < 8; ++j) {
      const __bf16* kr = &qk[(j * 8 + ni) * QS3 + 96 + ro];
      float acc = 0.f;
      for (int d = 0; d < 32; ++d) acc += q[d] * (float)kr[d];
      acc *= SCALE;
      s[j] = acc; mx = fmaxf(mx, acc);
    }
    float sum = 0.f;
    for (int j = 0; j < 8; ++j) { s[j] = __expf(s[j] - mx); sum += s[j]; }
    float inv = 1.f / sum;
    float o[32];
    for (int d = 0; d < 32; ++d) o[d] = 0.f;
    for (int j = 0; j < 8; ++j) {
      float p = s[j] * inv;
      const __bf16* vr = &qk[(j * 8 + ni) * QS3 + 192 + ro];
      for (int d = 0; d < 32; ++d) o[d] += p * (float)vr[d];
    }
    for (int d = 0; d < 32; ++d) ctx[(i * 8 + ni) * CS + ro + d] = (__bf16)o[d];
  }
  __syncthreads();

  // ---- phase C: proj -> out (x_t region), B fragments from L2 ----
  for (int tile = wave; tile < 24; tile += 4) {
    int rt = tile / 6, ct = tile % 6;
    int col = ct * 16 + lr;
    const __bf16* wrow = &WpT[col * 96 + quad * 8];
    f32x4 acc = {0.f, 0.f, 0.f, 0.f};
    for (int ks = 0; ks < 3; ++ks) {
      bf16x8 a  = *(const bf16x8*)&ctx[(rt * 16 + lr) * CS + ks * 32 + quad * 8];
      bf16x8 bb = *(const bf16x8*)&wrow[ks * 32];
      acc = MFMA(a, bb, acc, 0, 0, 0);
    }
    float bv = bp[col];
    for (int i = 0; i < 4; ++i) {
      int r = rt * 16 + quad * 4 + i;              // r = t*8 + ni
      int t = r >> 3, n = n0 + (r & 7);
      if (n < 49) out[((long)(b * 8 + t) * 49 + n) * 96 + col] = acc[i] + bv;
    }
  }
}

extern "C" void kernel_launch(void* const* d_in, const int* in_sizes, int n_in,
                              void* d_out, int out_size, void* d_ws, size_t ws_size,
                              hipStream_t stream) {
  const float* x         = (const float*)d_in[0];
  const float* mask      = (const float*)d_in[1];
  const float* qkv_w     = (const float*)d_in[2];
  const float* qkv_b     = (const float*)d_in[3];
  const float* proj_sp_w = (const float*)d_in[4];
  const float* proj_sp_b = (const float*)d_in[5];
  const float* proj_t_w  = (const float*)d_in[6];
  const float* proj_t_b  = (const float*)d_in[7];
  float* out = (float*)d_out;                      // [x_t | x_sp], each 401408*96
  __bf16* wsb = (__bf16*)d_ws;                     // 92,160 B used

  const __bf16* WqT  = wsb;                        // 288x96
  const __bf16* WspT = wsb + 27648;                // 96x96
  const __bf16* WtmT = wsb + 36864;                // 96x96

  k_transpose<<<dim3(3), dim3(256), 0, stream>>>(qkv_w, proj_sp_w, proj_t_w, wsb);
  k_spatial<<<dim3(8192), dim3(256), 0, stream>>>(x, WqT, qkv_b, mask, WspT,
                                                  proj_sp_b, out + 38535168);
  k_temporal<<<dim3(7, 1024), dim3(256), 0, stream>>>(x, WqT, qkv_b, WtmT,
                                                      proj_t_b, out);
}

// Round 2
// 665.233 us; speedup vs baseline: 2.0426x; 1.2260x over previous
//
#include <hip/hip_runtime.h>

// Round 5: 512-thread blocks (2 blocks/CU -> 16 waves/CU, was 8) for both
// kernels; k_temporal attention MFMA-ized (was 192-thread scalar loops):
//  - temporal x staged ni-major (row s = ni*8+t) so each ni-pair is 16
//    contiguous qkv rows -> scores = 1 MFMA per (head, pair), block-diagonal;
//    softmax over 8-lane key groups via shfl_xor; P written block-diagonal
//    with exact zeros (garbage lanes write 0, partner block zeroed inline).
//  - V written transposed in qkv epilogue for both kernels; PV/proj identical.
//  - spatial mask loads hoisted out of the head loop (3x fewer).
// mfma_f32_16x16x32_bf16: A[m=lane&15][k=quad*8+j], B[n=lane&15][k=quad*8+j],
//                         C/D: col=lane&15, row=quad*4+reg
typedef __bf16 bf16x2 __attribute__((ext_vector_type(2)));
typedef __bf16 bf16x4 __attribute__((ext_vector_type(4)));
typedef __bf16 bf16x8 __attribute__((ext_vector_type(8)));
typedef float f32x4 __attribute__((ext_vector_type(4)));
#define MFMA __builtin_amdgcn_mfma_f32_16x16x32_bf16

#define SCALE 0.17677669529663687f   // 1/sqrt(32)
#define QS2 200  // Q|K LDS row stride (bf16); 400B rows -> <=2-way b128 conflicts
#define VS 72    // VT row stride (bf16)
#define PS 72    // P row stride (bf16)
#define CS 104   // xt/ctx row stride (bf16)

__device__ __forceinline__ bf16x4 cvt4(const float* p) {
  bf16x4 v;
  float4 f = *(const float4*)p;
  v[0] = (__bf16)f.x; v[1] = (__bf16)f.y; v[2] = (__bf16)f.z; v[3] = (__bf16)f.w;
  return v;
}
__device__ __forceinline__ bf16x4 bz4() {
  bf16x4 z;
  for (int i = 0; i < 4; ++i) z[i] = (__bf16)0.f;
  return z;
}

// ---- K0: transpose+convert weights into ws: WqT[288x96] | WspT[96x96] | WtmT[96x96] ----
__global__ __launch_bounds__(256) void k_transpose(const float* __restrict__ Wq,
    const float* __restrict__ Wsp, const float* __restrict__ Wtm,
    __bf16* __restrict__ ws) {
  const int which = blockIdx.x, tid = threadIdx.x;
  if (which == 0) {
    for (int idx = tid; idx < 27648; idx += 256) {
      int n = idx / 96, k = idx % 96;
      ws[idx] = (__bf16)Wq[k * 288 + n];          // WqT[n][k] = Wq[k][n]
    }
  } else {
    const float* src = (which == 1) ? Wsp : Wtm;
    __bf16* dst = ws + 27648 + (which - 1) * 9216;
    for (int idx = tid; idx < 9216; idx += 256) {
      int n = idx / 96, k = idx % 96;
      dst[idx] = (__bf16)src[k * 96 + n];
    }
  }
}

// ---- K1: spatial: per (b,t): qkv, masked attn (L=49), proj_sp ----
// smem regions (bytes):
//   [0,25600)      qk (Q|K, 64 x QS2)      -> ctx (64 x CS) after scores
//   [25600,53248)  xt (64 x CS, phase A)   -> P (192 x PS) from phase B
//   [53248,67072)  VT (96 x VS)
__global__ __launch_bounds__(512, 4) void k_spatial(const float* __restrict__ x,
    const __bf16* __restrict__ WqT, const float* __restrict__ qkv_b,
    const float* __restrict__ mask, const __bf16* __restrict__ WpT,
    const float* __restrict__ bp, float* __restrict__ out) {
  __shared__ __align__(16) char smem[67072];
  __bf16* qk  = (__bf16*)(smem);
  __bf16* ctx = (__bf16*)(smem);
  __bf16* xt  = (__bf16*)(smem + 25600);
  __bf16* P   = (__bf16*)(smem + 25600);
  __bf16* VT  = (__bf16*)(smem + 53248);

  const int tid = threadIdx.x;
  const int bt = blockIdx.x;                      // b*8 + t
  const long rbase = (long)bt * 49;
  const int wave = tid >> 6, lane = tid & 63, lr = lane & 15, quad = lane >> 4;

  // ---- phase A: stage x tile (fp32->bf16, pad rows zero); qkv MFMA ----
  const float* xg = x + rbase * 96;
  for (int v = tid; v < 1536; v += 512) {         // 64 rows x 24 float4
    int r = v / 24, c = (v % 24) * 4;
    bf16x4 val = bz4();
    if (r < 49) val = cvt4(&xg[r * 96 + c]);
    *(bf16x4*)&xt[r * CS + c] = val;
  }
  __syncthreads();
  {
    bf16x8 afr[4][3];                             // A fragments in regs
    for (int rt = 0; rt < 4; ++rt)
      for (int ks = 0; ks < 3; ++ks)
        afr[rt][ks] = *(const bf16x8*)&xt[(rt * 16 + lr) * CS + ks * 32 + quad * 8];
    for (int ct = wave; ct < 18; ct += 8) {       // B fragments straight from L2
      const __bf16* wrow = &WqT[(ct * 16 + lr) * 96 + quad * 8];
      bf16x8 b0 = *(const bf16x8*)&wrow[0];
      bf16x8 b1 = *(const bf16x8*)&wrow[32];
      bf16x8 b2 = *(const bf16x8*)&wrow[64];
      int col = ct * 16 + lr;
      float bv = qkv_b[col];
      for (int rt = 0; rt < 4; ++rt) {
        f32x4 acc = {0.f, 0.f, 0.f, 0.f};
        acc = MFMA(afr[rt][0], b0, acc, 0, 0, 0);
        acc = MFMA(afr[rt][1], b1, acc, 0, 0, 0);
        acc = MFMA(afr[rt][2], b2, acc, 0, 0, 0);
        if (ct < 12) {                            // Q|K -> qk rows
          for (int i = 0; i < 4; ++i)
            qk[(rt * 16 + quad * 4 + i) * QS2 + col] = (__bf16)(acc[i] + bv);
        } else {                                  // V -> VT transposed, packed 4B
          int d = col - 192;
          __bf16* vp = &VT[d * VS + rt * 16 + quad * 4];
          bf16x2 lo; lo[0] = (__bf16)(acc[0] + bv); lo[1] = (__bf16)(acc[1] + bv);
          bf16x2 hi; hi[0] = (__bf16)(acc[2] + bv); hi[1] = (__bf16)(acc[3] + bv);
          *(bf16x2*)&vp[0] = lo;
          *(bf16x2*)&vp[2] = hi;
        }
      }
    }
  }
  __syncthreads();                                // xt dead; P takes its region

  // ---- phase B: scores + wave-parallel register softmax -> P ----
  // task = (rt = task&3 == wave&3, h = task>>2). m>=49 forced to -1e30.
  {
    const int rt = wave & 3;
    const int nb = rt * 16 + quad * 4;
    const float* mrow = mask + (long)(bt & 63) * 2401;
    float mv[4][4];                               // hoisted: same for all heads
    for (int ct = 0; ct < 4; ++ct) {
      int m = ct * 16 + lr;
      int mm = (m < 49) ? m : 48;
      for (int i = 0; i < 4; ++i) {
        int nn = (nb + i < 49) ? nb + i : 48;
        mv[ct][i] = mrow[nn * 49 + mm];
      }
    }
    for (int task = wave; task < 12; task += 8) {
      int h = task >> 2;
      bf16x8 qf = *(const bf16x8*)&qk[(rt * 16 + lr) * QS2 + h * 32 + quad * 8];
      float sv[4][4];
      for (int ct = 0; ct < 4; ++ct) {
        bf16x8 kf = *(const bf16x8*)&qk[(ct * 16 + lr) * QS2 + 96 + h * 32 + quad * 8];
        f32x4 acc = {0.f, 0.f, 0.f, 0.f};
        acc = MFMA(qf, kf, acc, 0, 0, 0);
        int m = ct * 16 + lr;
        for (int i = 0; i < 4; ++i)
          sv[ct][i] = (m < 49) ? (acc[i] * SCALE + mv[ct][i]) : -1e30f;
      }
      for (int i = 0; i < 4; ++i) {
        float mx = fmaxf(fmaxf(sv[0][i], sv[1][i]), fmaxf(sv[2][i], sv[3][i]));
        mx = fmaxf(mx, __shfl_xor(mx, 1));
        mx = fmaxf(mx, __shfl_xor(mx, 2));
        mx = fmaxf(mx, __shfl_xor(mx, 4));
        mx = fmaxf(mx, __shfl_xor(mx, 8));
        float e0 = __expf(sv[0][i] - mx), e1 = __expf(sv[1][i] - mx);
        float e2 = __expf(sv[2][i] - mx), e3 = __expf(sv[3][i] - mx);
        float sum = e0 + e1 + e2 + e3;
        sum += __shfl_xor(sum, 1);
        sum += __shfl_xor(sum, 2);
        sum += __shfl_xor(sum, 4);
        sum += __shfl_xor(sum, 8);
        float inv = 1.f / sum;
        __bf16* Pr = &P[(h * 64 + nb + i) * PS + lr];
        Pr[0]  = (__bf16)(e0 * inv);
        Pr[16] = (__bf16)(e1 * inv);
        Pr[32] = (__bf16)(e2 * inv);
        Pr[48] = (__bf16)(e3 * inv);
      }
    }
  }
  __syncthreads();                                // qk dead; ctx takes its region

  // ---- phase C: PV -> ctx ----
  for (int tile = wave; tile < 24; tile += 8) {
    int h = tile / 8, rt = (tile / 2) & 3, dt = tile & 1;
    f32x4 acc = {0.f, 0.f, 0.f, 0.f};
    for (int ks = 0; ks < 2; ++ks) {
      bf16x8 a  = *(const bf16x8*)&P[(h * 64 + rt * 16 + lr) * PS + ks * 32 + quad * 8];
      bf16x8 bb = *(const bf16x8*)&VT[(h * 32 + dt * 16 + lr) * VS + ks * 32 + quad * 8];
      acc = MFMA(a, bb, acc, 0, 0, 0);
    }
    for (int i = 0; i < 4; ++i)
      ctx[(rt * 16 + quad * 4 + i) * CS + h * 32 + dt * 16 + lr] = (__bf16)acc[i];
  }
  __syncthreads();

  // ---- phase D: proj -> out, B fragments from L2 ----
  for (int tile = wave; tile < 24; tile += 8) {
    int rt = tile / 6, ct = tile % 6;
    int col = ct * 16 + lr;
    const __bf16* wrow = &WpT[col * 96 + quad * 8];
    f32x4 acc = {0.f, 0.f, 0.f, 0.f};
    for (int ks = 0; ks < 3; ++ks) {
      bf16x8 a  = *(const bf16x8*)&ctx[(rt * 16 + lr) * CS + ks * 32 + quad * 8];
      bf16x8 bb = *(const bf16x8*)&wrow[ks * 32];
      acc = MFMA(a, bb, acc, 0, 0, 0);
    }
    float bv = bp[col];
    for (int i = 0; i < 4; ++i) {
      int r = rt * 16 + quad * 4 + i;
      if (r < 49) out[(rbase + r) * 96 + col] = acc[i] + bv;
    }
  }
}

// ---- K2: temporal: per (b, 8-n group): qkv, per-window 8x8 attn via MFMA, proj ----
// Storage row s = ni*8 + t (ni-major) -> pair p covers 16 contiguous rows.
// smem layout identical to k_spatial.
__global__ __launch_bounds__(512, 4) void k_temporal(const float* __restrict__ x,
    const __bf16* __restrict__ WqT, const float* __restrict__ qkv_b,
    const __bf16* __restrict__ WpT, const float* __restrict__ bp,
    float* __restrict__ out) {
  __shared__ __align__(16) char smem[67072];
  __bf16* qk  = (__bf16*)(smem);
  __bf16* ctx = (__bf16*)(smem);
  __bf16* xt  = (__bf16*)(smem + 25600);
  __bf16* P   = (__bf16*)(smem + 25600);          // 3 heads x 64 x PS, block-diagonal
  __bf16* VT  = (__bf16*)(smem + 53248);

  const int tid = threadIdx.x;
  const int n0 = blockIdx.x * 8;
  const int b = blockIdx.y;
  const int wave = tid >> 6, lane = tid & 63, lr = lane & 15, quad = lane >> 4;

  // ---- phase A: stage x rows s = ni*8+t (fp32->bf16); qkv MFMA ----
  for (int v = tid; v < 1536; v += 512) {
    int s = v / 24, c = (v % 24) * 4;
    int ni = s >> 3, t = s & 7, n = n0 + ni;
    bf16x4 val = bz4();
    if (n < 49) val = cvt4(&x[((long)(b * 8 + t) * 49 + n) * 96 + c]);
    *(bf16x4*)&xt[s * CS + c] = val;
  }
  __syncthreads();
  {
    bf16x8 afr[4][3];
    for (int rt = 0; rt < 4; ++rt)
      for (int ks = 0; ks < 3; ++ks)
        afr[rt][ks] = *(const bf16x8*)&xt[(rt * 16 + lr) * CS + ks * 32 + quad * 8];
    for (int ct = wave; ct < 18; ct += 8) {
      const __bf16* wrow = &WqT[(ct * 16 + lr) * 96 + quad * 8];
      bf16x8 b0 = *(const bf16x8*)&wrow[0];
      bf16x8 b1 = *(const bf16x8*)&wrow[32];
      bf16x8 b2 = *(const bf16x8*)&wrow[64];
      int col = ct * 16 + lr;
      float bv = qkv_b[col];
      for (int rt = 0; rt < 4; ++rt) {
        f32x4 acc = {0.f, 0.f, 0.f, 0.f};
        acc = MFMA(afr[rt][0], b0, acc, 0, 0, 0);
        acc = MFMA(afr[rt][1], b1, acc, 0, 0, 0);
        acc = MFMA(afr[rt][2], b2, acc, 0, 0, 0);
        if (ct < 12) {
          for (int i = 0; i < 4; ++i)
            qk[(rt * 16 + quad * 4 + i) * QS2 + col] = (__bf16)(acc[i] + bv);
        } else {
          int d = col - 192;
          __bf16* vp = &VT[d * VS + rt * 16 + quad * 4];
          bf16x2 lo; lo[0] = (__bf16)(acc[0] + bv); lo[1] = (__bf16)(acc[1] + bv);
          bf16x2 hi; hi[0] = (__bf16)(acc[2] + bv); hi[1] = (__bf16)(acc[3] + bv);
          *(bf16x2*)&vp[0] = lo;
          *(bf16x2*)&vp[2] = hi;
        }
      }
    }
  }
  __syncthreads();                                // xt dead; P takes its region

  // ---- phase B: block-diagonal scores via MFMA + 8-lane softmax -> P ----
  // MFMA on rows p*16..p*16+15 gives S[(nl,tq)][(nl',tk)]; useful iff nl==nl'
  // (lane useful iff (lane&15)>>3 == lane>>5). Softmax over tk = 8-lane xor group.
  // P row h*64+p*16+m gets exact 0 off-diagonal + partner block zeroed inline.
  {
    const bool useful = (((lane & 15) >> 3) == (lane >> 5));
    for (int task = wave; task < 12; task += 8) {
      int p = task & 3, h = task >> 2;
      bf16x8 qf = *(const bf16x8*)&qk[(p * 16 + lr) * QS2 + h * 32 + quad * 8];
      bf16x8 kf = *(const bf16x8*)&qk[(p * 16 + lr) * QS2 + 96 + h * 32 + quad * 8];
      f32x4 acc = {0.f, 0.f, 0.f, 0.f};
      acc = MFMA(qf, kf, acc, 0, 0, 0);
      for (int rr = 0; rr < 4; ++rr) {
        float s = acc[rr] * SCALE;
        float mx = s;
        mx = fmaxf(mx, __shfl_xor(mx, 1));
        mx = fmaxf(mx, __shfl_xor(mx, 2));
        mx = fmaxf(mx, __shfl_xor(mx, 4));
        float e = __expf(s - mx);
        float sum = e;
        sum += __shfl_xor(sum, 1);
        sum += __shfl_xor(sum, 2);
        sum += __shfl_xor(sum, 4);
        float pv = useful ? (e / sum) : 0.f;
        int row = h * 64 + p * 16 + quad * 4 + rr;
        P[row * PS + p * 16 + (lane & 15)] = (__bf16)pv;
        P[row * PS + (p ^ 1) * 16 + (lane & 15)] = (__bf16)0.f;
      }
    }
  }
  __syncthreads();                                // qk dead; ctx takes its region

  // ---- phase C: PV -> ctx. k-window (pt>>1)*32 covers own + zeroed partner. ----
  for (int task = wave; task < 24; task += 8) {
    int h = task >> 3, pt = (task >> 1) & 3, dh = task & 1;
    bf16x8 a  = *(const bf16x8*)&P[(h * 64 + pt * 16 + lr) * PS + (pt >> 1) * 32 + quad * 8];
    bf16x8 bb = *(const bf16x8*)&VT[(h * 32 + dh * 16 + lr) * VS + (pt >> 1) * 32 + quad * 8];
    f32x4 acc = {0.f, 0.f, 0.f, 0.f};
    acc = MFMA(a, bb, acc, 0, 0, 0);
    for (int i = 0; i < 4; ++i)
      ctx[(pt * 16 + quad * 4 + i) * CS + h * 32 + dh * 16 + lr] = (__bf16)acc[i];
  }
  __syncthreads();

  // ---- phase D: proj -> out (x_t region); row s -> t=s&7, n=n0+(s>>3) ----
  for (int tile = wave; tile < 24; tile += 8) {
    int rt = tile / 6, ct = tile % 6;
    int col = ct * 16 + lr;
    const __bf16* wrow = &WpT[col * 96 + quad * 8];
    f32x4 acc = {0.f, 0.f, 0.f, 0.f};
    for (int ks = 0; ks < 3; ++ks) {
      bf16x8 a  = *(const bf16x8*)&ctx[(rt * 16 + lr) * CS + ks * 32 + quad * 8];
      bf16x8 bb = *(const bf16x8*)&wrow[ks * 32];
      acc = MFMA(a, bb, acc, 0, 0, 0);
    }
    float bv = bp[col];
    for (int i = 0; i < 4; ++i) {
      int s = rt * 16 + quad * 4 + i;
      int t = s & 7, n = n0 + (s >> 3);
      if (n < 49) out[((long)(b * 8 + t) * 49 + n) * 96 + col] = acc[i] + bv;
    }
  }
}

extern "C" void kernel_launch(void* const* d_in, const int* in_sizes, int n_in,
                              void* d_out, int out_size, void* d_ws, size_t ws_size,
                              hipStream_t stream) {
  const float* x         = (const float*)d_in[0];
  const float* mask      = (const float*)d_in[1];
  const float* qkv_w     = (const float*)d_in[2];
  const float* qkv_b     = (const float*)d_in[3];
  const float* proj_sp_w = (const float*)d_in[4];
  const float* proj_sp_b = (const float*)d_in[5];
  const float* proj_t_w  = (const float*)d_in[6];
  const float* proj_t_b  = (const float*)d_in[7];
  float* out = (float*)d_out;                      // [x_t | x_sp], each 401408*96
  __bf16* wsb = (__bf16*)d_ws;                     // 92,160 B used

  const __bf16* WqT  = wsb;                        // 288x96
  const __bf16* WspT = wsb + 27648;                // 96x96
  const __bf16* WtmT = wsb + 36864;                // 96x96

  k_transpose<<<dim3(3), dim3(256), 0, stream>>>(qkv_w, proj_sp_w, proj_t_w, wsb);
  k_spatial<<<dim3(8192), dim3(512), 0, stream>>>(x, WqT, qkv_b, mask, WspT,
                                                  proj_sp_b, out + 38535168);
  k_temporal<<<dim3(7, 1024), dim3(512), 0, stream>>>(x, WqT, qkv_b, WtmT,
                                                      proj_t_b, out);
}